// Round 6
// baseline (328.954 us; speedup 1.0000x reference)
//
#include <hip/hip_runtime.h>
#include <stdint.h>
#include <math.h>

typedef unsigned short u16;
typedef __attribute__((ext_vector_type(8))) short short8;
typedef __attribute__((ext_vector_type(8))) u16 ushort8;
typedef __attribute__((ext_vector_type(4))) u16 u16x4;
typedef __attribute__((ext_vector_type(4))) float floatx4;

__device__ __forceinline__ u16 f2bf(float f) {
  union { float f; unsigned u; } c; c.f = f;
  unsigned u = c.u;
  return (u16)((u + 0x7fffu + ((u >> 16) & 1u)) >> 16);
}
__device__ __forceinline__ float bf2f(u16 h) {
  union { unsigned u; float f; } c; c.u = (unsigned)h << 16;
  return c.f;
}

// async global->LDS, 16 bytes per lane; LDS dest must be lane-contiguous.
__device__ __forceinline__ void async16(const u16* g, u16* l) {
  auto* gp = reinterpret_cast<const __attribute__((address_space(1))) uint32_t*>(
      reinterpret_cast<uintptr_t>(g));
  auto* lp = reinterpret_cast<__attribute__((address_space(3))) uint32_t*>(
      reinterpret_cast<uintptr_t>(l));
  __builtin_amdgcn_global_load_lds(gp, lp, 16, 0, 0);
}

// s_waitcnt immediates (gfx9 encoding): vmcnt[3:0] | expcnt<<4 | lgkmcnt<<8
#define WAIT_VM4 0xF74  // vmcnt(4): wait until <=4 vmem ops outstanding
#define WAIT_VM0 0xF70  // vmcnt(0)

// ---------------------------------------------------------------------------
// C = A * B^T.  A: [M][K] bf16 row-major (lda), B: [N][K] bf16 row-major (ldb).
// 256 threads = 4 waves, 128x128 tile, per-wave 64x64.  ~4 blocks/CU
// (52 VGPR + 64 AGPR, 32 KB LDS) -> occupancy hides the barrier drain.
// Double-buffered LDS + vmcnt(4) pipeline.  16B-seg XOR swizzle.
// tri_grid: blockIdx.x enumerates lower-triangle tiles (S gemm), with a
//   bijective XCD swizzle (136 = 8 XCDs x 17 chunks) for qp/kp L2 locality.
// splitk (out gemm): grid.x = 24 slots:
//   bx 0..7   -> bm = 8+bx, K part [0,1024)    (heaviest first)
//   bx 8..15  -> bm = 15-(bx-8), K part [1024, klimit)
//   bx 16..23 -> bm = 23-bx (7..0), full K (single writer)
//   split tiles (bm>=8) have two writers -> unsafeAtomicAdd onto zeroed C.
//   (exact: fl(a+b) is order-independent for two addends on a zeroed base)
// vpt: writes C transposed as [4][1024][2048] (vp^T direct).
// ---------------------------------------------------------------------------
template <int OUT_BF16>
__global__ __launch_bounds__(256) void gemm_bt(
    const u16* __restrict__ A, const u16* __restrict__ B, void* __restrict__ Cv,
    int K, int lda, int ldb, int ldc,
    long long sA, long long sB, long long sC,
    float scale, int tri_grid, int causal_klimit, int splitk,
    int vpt, u16* __restrict__ vpC) {
  int bm, bn;
  int kt0 = 0;
  bool part0_heavy = false;
  bool atomic_out = false;
  if (tri_grid) {
    int bx = blockIdx.x;
    bx = (bx & 7) * 17 + (bx >> 3);  // bijective XCD swizzle (136 = 8*17)
    int i = (int)((sqrtf(8.f * bx + 1.f) - 1.f) * 0.5f);
    while ((i + 1) * (i + 2) / 2 <= bx) ++i;
    while (i * (i + 1) / 2 > bx) --i;
    bm = i;
    bn = bx - i * (i + 1) / 2;
  } else if (splitk) {
    const int bx = blockIdx.x;  // 0..23
    if (bx < 8) {
      bm = 8 + bx; part0_heavy = true; atomic_out = true;
    } else if (bx < 16) {
      bm = 15 - (bx - 8); kt0 = 32; atomic_out = true;
    } else {
      bm = 23 - bx;
    }
    bn = blockIdx.y;
  } else {
    bm = blockIdx.x;
    bn = blockIdx.y;
  }
  const int m0 = bm * 128;
  const int n0 = bn * 128;
  A += (size_t)blockIdx.z * sA;
  B += (size_t)blockIdx.z * sB;

  __shared__ u16 As[2][4096];
  __shared__ u16 Bs[2][4096];

  const int tid = threadIdx.x;
  const int lane = tid & 63;
  const int wid = tid >> 6;
  const int wm = (wid & 1) * 64;
  const int wn = (wid >> 1) * 64;
  const int fr = lane & 15;   // m/n within 16x16 frag
  const int fq = lane >> 4;   // logical k-segment

  floatx4 acc[4][4] = {};

  int kt_end = K >> 5;
  if (causal_klimit) {
    int lim = (m0 >> 5) + 4;
    if (lim < kt_end) kt_end = lim;
  }
  if (part0_heavy && kt_end > 32) kt_end = 32;

  const int rowi = tid >> 2;                 // 0..63
  const int segi = tid & 3;                  // physical 16B seg
  const int sgz = segi ^ ((rowi >> 1) & 3);  // logical seg to fetch
  const u16* gA = A + (size_t)(m0 + rowi) * lda + sgz * 8;
  const u16* gB = B + (size_t)(n0 + rowi) * ldb + sgz * 8;

  // fragment read offsets (swizzled), within one 4096-elem buffer
  int offA[4], offB[4];
#pragma unroll
  for (int i = 0; i < 4; ++i) {
    int ra = wm + i * 16 + fr;
    offA[i] = ra * 32 + (fq ^ ((ra >> 1) & 3)) * 8;
    int rb = wn + i * 16 + fr;
    offB[i] = rb * 32 + (fq ^ ((rb >> 1) & 3)) * 8;
  }

  auto issue = [&](int kt) {
    const int k0 = kt << 5;
    const int odd = kt & 1;
    async16(gA + k0, &As[odd][tid * 8]);
    async16(gA + k0 + (size_t)64 * lda, &As[odd][tid * 8 + 2048]);
    async16(gB + k0, &Bs[odd][tid * 8]);
    async16(gB + k0 + (size_t)64 * ldb, &Bs[odd][tid * 8 + 2048]);
  };

  issue(kt0);
  for (int kt = kt0; kt < kt_end; ++kt) {
    if (kt + 1 < kt_end) {
      issue(kt + 1);
      __builtin_amdgcn_s_waitcnt(WAIT_VM4);  // tile kt's 4 loads retired
    } else {
      __builtin_amdgcn_s_waitcnt(WAIT_VM0);
    }
    asm volatile("s_barrier" ::: "memory");

    const u16* ab = As[kt & 1];
    const u16* bb = Bs[kt & 1];
    short8 av[4], bv[4];
#pragma unroll
    for (int i = 0; i < 4; ++i) av[i] = *(const short8*)(ab + offA[i]);
#pragma unroll
    for (int j = 0; j < 4; ++j) bv[j] = *(const short8*)(bb + offB[j]);

#pragma unroll
    for (int i = 0; i < 4; ++i)
#pragma unroll
      for (int j = 0; j < 4; ++j)
        acc[i][j] = __builtin_amdgcn_mfma_f32_16x16x32_bf16(av[i], bv[j],
                                                            acc[i][j], 0, 0, 0);
    asm volatile("s_barrier" ::: "memory");  // readers done before overwrite
  }

  // Epilogue. C/D layout: col = lane&15 (=fr), row = fq*4 + reg.
  if (vpt) {
    // write transposed: vpC[b][n][t], b = m>>11, t = m&2047 (T=2048, H=1024)
#pragma unroll
    for (int i = 0; i < 4; ++i) {
      const int m = m0 + wm + i * 16 + fq * 4;
      const int b = m >> 11, t = m & 2047;
#pragma unroll
      for (int j = 0; j < 4; ++j) {
        const int n = n0 + wn + j * 16 + fr;
        u16x4 o;
#pragma unroll
        for (int r = 0; r < 4; ++r) o[r] = f2bf(acc[i][j][r]);
        *(u16x4*)&vpC[(size_t)b * 2097152 + (size_t)n * 2048 + t] = o;
      }
    }
    return;
  }
  if (OUT_BF16) {
    u16* C = (u16*)Cv + (size_t)blockIdx.z * sC;
#pragma unroll
    for (int i = 0; i < 4; ++i) {
      const int m = m0 + wm + i * 16 + fq * 4;
#pragma unroll
      for (int j = 0; j < 4; ++j) {
        const int n = n0 + wn + j * 16 + fr;
#pragma unroll
        for (int r = 0; r < 4; ++r)
          C[(size_t)(m + r) * ldc + n] = f2bf(acc[i][j][r] * scale);
      }
    }
  } else {
    float* C = (float*)Cv + (size_t)blockIdx.z * sC;
    if (atomic_out) {
#pragma unroll
      for (int i = 0; i < 4; ++i) {
        const int m = m0 + wm + i * 16 + fq * 4;
#pragma unroll
        for (int j = 0; j < 4; ++j) {
          const int n = n0 + wn + j * 16 + fr;
#pragma unroll
          for (int r = 0; r < 4; ++r)
            unsafeAtomicAdd(&C[(size_t)(m + r) * ldc + n],
                            acc[i][j][r] * scale);
        }
      }
    } else {
#pragma unroll
      for (int i = 0; i < 4; ++i) {
        const int m = m0 + wm + i * 16 + fq * 4;
#pragma unroll
        for (int j = 0; j < 4; ++j) {
          const int n = n0 + wn + j * 16 + fr;
#pragma unroll
          for (int r = 0; r < 4; ++r)
            C[(size_t)(m + r) * ldc + n] = acc[i][j][r] * scale;
        }
      }
    }
  }
}

// Zero the atomic-accumulation region: out[z][1024:2048][:] for z=0..3.
// 4 batches x 1024 rows x 1024 cols f32 = 16 MB; float4 grid-stride.
__global__ __launch_bounds__(256) void zero_splitk(float* __restrict__ out) {
  const size_t i = (size_t)blockIdx.x * 256 + threadIdx.x;  // float4 index
  // region: for each z, floats [z*2097152 + 1048576, z*2097152 + 2097152)
  const size_t z = i >> 18;          // 262144 float4 per batch-half
  const size_t r = i & 262143;
  floatx4* p = (floatx4*)(out + z * 2097152 + 1048576) + r;
  *p = floatx4{0.f, 0.f, 0.f, 0.f};
}

// fp32 -> bf16 cast for q,k,v in one dispatch (blockIdx.y selects source)
__global__ __launch_bounds__(256) void cast3(
    const float* __restrict__ q, const float* __restrict__ k,
    const float* __restrict__ v, u16* __restrict__ out, int n8) {
  int i = blockIdx.x * 256 + threadIdx.x;
  if (i >= n8) return;
  const float* src = blockIdx.y == 0 ? q : (blockIdx.y == 1 ? k : v);
  u16* dst = out + (size_t)blockIdx.y * n8 * 8;
  floatx4 a = ((const floatx4*)src)[i * 2];
  floatx4 b = ((const floatx4*)src)[i * 2 + 1];
  ushort8 o;
#pragma unroll
  for (int j = 0; j < 4; ++j) { o[j] = f2bf(a[j]); o[4 + j] = f2bf(b[j]); }
  ((ushort8*)dst)[i] = o;
}

// fp32 [R][C] -> bf16 [C][R] transpose+cast, 64x64 tiles; z picks (Wq,Wk,Wq)
__global__ __launch_bounds__(256) void transpose_castW(
    const float* __restrict__ Wq, const float* __restrict__ Wk,
    u16* __restrict__ out, int R, int C) {
  __shared__ u16 tile[64][72];
  const float* in = (blockIdx.z == 1) ? Wk : Wq;
  u16* dst = out + (size_t)blockIdx.z * R * C;
  const int r0 = blockIdx.x * 64;
  const int c0 = blockIdx.y * 64;
  const int tid = threadIdx.x;
#pragma unroll
  for (int rnd = 0; rnd < 2; ++rnd) {
    int e = rnd * 256 + tid;
    int rr = e >> 3, seg = e & 7;
    const float* p = &in[(size_t)(r0 + rr) * C + c0 + seg * 8];
    floatx4 a = *(const floatx4*)p;
    floatx4 b = *(const floatx4*)(p + 4);
    u16* tp = &tile[rr][seg * 8];
#pragma unroll
    for (int j = 0; j < 4; ++j) { tp[j] = f2bf(a[j]); tp[4 + j] = f2bf(b[j]); }
  }
  __syncthreads();
#pragma unroll
  for (int rnd = 0; rnd < 2; ++rnd) {
    int e = rnd * 256 + tid;
    int cc = e >> 3, rseg = e & 7;
    ushort8 tv;
#pragma unroll
    for (int j = 0; j < 8; ++j) tv[j] = tile[rseg * 8 + j][cc];
    *(ushort8*)&dst[(size_t)(c0 + cc) * R + r0 + rseg * 8] = tv;
  }
}

// Causal row softmax, bf16 in-place, single pass (T=2048).
// All per-thread state statically indexed (rule #20); one 16B load + one 16B
// store per thread; masked lanes write exp(-huge)*inv = 0 (upper-tri fill).
__global__ __launch_bounds__(256) void softmax_causal(u16* __restrict__ S,
                                                      int T) {
  const int row = blockIdx.x;
  const int t = row & (T - 1);
  const int len = t + 1;
  u16* srow = S + (size_t)row * T;
  const int tid = threadIdx.x;
  const int base = tid * 8;

  const ushort8 raw = *(const ushort8*)(srow + base);
  float v[8];
  float mx = -1e30f;
#pragma unroll
  for (int j = 0; j < 8; ++j) {
    const float f = bf2f(raw[j]);
    v[j] = (base + j < len) ? f : -1e30f;
    mx = fmaxf(mx, v[j]);
  }
#pragma unroll
  for (int o = 32; o > 0; o >>= 1) mx = fmaxf(mx, __shfl_xor(mx, o, 64));

  __shared__ float red[8];
  if ((tid & 63) == 0) red[tid >> 6] = mx;
  __syncthreads();
  mx = fmaxf(fmaxf(red[0], red[1]), fmaxf(red[2], red[3]));

  float sum = 0.f;
#pragma unroll
  for (int j = 0; j < 8; ++j) {
    const float e = __expf(v[j] - mx);  // masked lanes: exp(-huge) = 0
    v[j] = e;
    sum += e;
  }
#pragma unroll
  for (int o = 32; o > 0; o >>= 1) sum += __shfl_xor(sum, o, 64);
  if ((tid & 63) == 0) red[4 + (tid >> 6)] = sum;
  __syncthreads();
  sum = red[4] + red[5] + red[6] + red[7];
  const float inv = 1.f / sum;

  ushort8 o8;
#pragma unroll
  for (int j = 0; j < 8; ++j) o8[j] = f2bf(v[j] * inv);
  *(ushort8*)(srow + base) = o8;
}

extern "C" void kernel_launch(void* const* d_in, const int* in_sizes, int n_in,
                              void* d_out, int out_size, void* d_ws,
                              size_t ws_size, hipStream_t stream) {
  (void)in_sizes; (void)n_in; (void)out_size; (void)ws_size;
  const float* k  = (const float*)d_in[1];
  const float* q  = (const float*)d_in[2];
  const float* v  = (const float*)d_in[3];
  const float* Wk = (const float*)d_in[4];
  const float* Wq = (const float*)d_in[5];
  float* out = (float*)d_out;

  const int B = 4, T = 2048, C = 1024, H = 1024;
  const int M = B * T;  // 8192
  const size_t MC = (size_t)M * C, CH = (size_t)C * H, MH = (size_t)M * H;

  u16* qkv  = (u16*)d_ws;        // 3 slots [M][C] bf16 (q,k,v)        50 MB
  u16* WT   = qkv + 3 * MC;      // 3 slots [H][C] bf16 (Wq,Wk,Wq)      6 MB
  u16* qkvp = WT + 3 * CH;       // slot0 qp, slot1 kp [M][H]          34 MB
  u16* vpT  = qkvp + 2 * MH;     // [B][H][T] bf16 (vp^T, direct)      17 MB
  u16* Sb   = vpT + MH;          // [B][T][T] bf16 (S, then P)       33.5 MB

  // zero the split-K atomic region (out[z][1024:2048][:], 16 MB) — kernel,
  // not hipMemsetAsync (graph-capture safety)
  zero_splitk<<<dim3(4096), 256, 0, stream>>>(out);

  const int n8 = (int)(MC / 8);
  cast3<<<dim3(n8 / 256, 3), 256, 0, stream>>>(q, k, v, qkv, n8);
  transpose_castW<<<dim3(C / 64, H / 64, 3), 256, 0, stream>>>(Wq, Wk, WT, C, H);

  // projections as 3 separate dispatches (top-5 visibility into S/out):
  // qp = q*Wq, kp = k*Wk, vp^T = (v*Wq)^T
  gemm_bt<1><<<dim3(M / 128, H / 128, 1), 256, 0, stream>>>(
      qkv, WT, qkvp, C, C, C, H, 0, 0, 0, 1.f, 0, 0, 0, 0, nullptr);
  gemm_bt<1><<<dim3(M / 128, H / 128, 1), 256, 0, stream>>>(
      qkv + MC, WT + CH, qkvp + MH, C, C, C, H, 0, 0, 0, 1.f, 0, 0, 0, 0,
      nullptr);
  gemm_bt<1><<<dim3(M / 128, H / 128, 1), 256, 0, stream>>>(
      qkv + 2 * MC, WT + 2 * CH, qkvp, C, C, C, H, 0, 0, 0, 1.f, 0, 0, 0, 1,
      vpT);

  // S = qp*kp^T / 32 (bf16 out), compact lower-triangle grid (136 tiles/batch)
  gemm_bt<1><<<dim3(136, 1, B), 256, 0, stream>>>(
      qkvp, qkvp + MH, Sb, H, H, H, T,
      (long long)T * H, (long long)T * H, (long long)T * T,
      0.03125f, 1, 0, 0, 0, nullptr);

  softmax_causal<<<dim3(B * T), 256, 0, stream>>>(Sb, T);

  // out = P * vpT^T, causal klimit, split-K (24 slots: heavy halves first)
  gemm_bt<0><<<dim3(24, H / 128, B), 256, 0, stream>>>(
      Sb, vpT, out, T, T, T, H,
      (long long)T * T, (long long)H * T, (long long)T * H,
      1.f, 0, 1, 1, 0, nullptr);
}

// Round 7
// 318.601 us; speedup vs baseline: 1.0325x; 1.0325x over previous
//
#include <hip/hip_runtime.h>
#include <stdint.h>
#include <math.h>

typedef unsigned short u16;
typedef __attribute__((ext_vector_type(8))) short short8;
typedef __attribute__((ext_vector_type(8))) u16 ushort8;
typedef __attribute__((ext_vector_type(4))) u16 u16x4;
typedef __attribute__((ext_vector_type(4))) float floatx4;

__device__ __forceinline__ u16 f2bf(float f) {
  union { float f; unsigned u; } c; c.f = f;
  unsigned u = c.u;
  return (u16)((u + 0x7fffu + ((u >> 16) & 1u)) >> 16);
}
__device__ __forceinline__ float bf2f(u16 h) {
  union { unsigned u; float f; } c; c.u = (unsigned)h << 16;
  return c.f;
}

// async global->LDS, 16 bytes per lane; LDS dest must be lane-contiguous.
__device__ __forceinline__ void async16(const u16* g, u16* l) {
  auto* gp = reinterpret_cast<const __attribute__((address_space(1))) uint32_t*>(
      reinterpret_cast<uintptr_t>(g));
  auto* lp = reinterpret_cast<__attribute__((address_space(3))) uint32_t*>(
      reinterpret_cast<uintptr_t>(l));
  __builtin_amdgcn_global_load_lds(gp, lp, 16, 0, 0);
}

// s_waitcnt immediates (gfx9 encoding): vmcnt[3:0] | expcnt<<4 | lgkmcnt<<8
#define WAIT_VM4 0xF74  // vmcnt(4): wait until <=4 vmem ops outstanding
#define WAIT_VM0 0xF70  // vmcnt(0)

// ---------------------------------------------------------------------------
// C = A * B^T.  A: [M][K] bf16 row-major (lda), B: [N][K] bf16 row-major (ldb).
// 256 threads = 4 waves, 128x128 tile, per-wave 64x64.  ~2.6 blocks/CU
// resident -> wave-level overlap hides the barrier drain.
// Double-buffered LDS + vmcnt(4) pipeline.  16B-seg XOR swizzle.
// tri_grid: blockIdx.x enumerates lower-triangle tiles (S gemm), with a
//   bijective XCD swizzle (136 = 8 XCDs x 17 chunks) for qp/kp L2 locality.
// SPLITK (out gemm, template): grid.x = 24 slots:
//   bx 0..7   -> bm = 8+bx, K part [0,1024)    (heaviest first)
//   bx 8..15  -> bm = 15-(bx-8), K part [1024, klimit)
//   bx 16..23 -> bm = 23-bx (7..0), full K (single writer)
//   split tiles (bm>=8) have two writers -> unsafeAtomicAdd onto zeroed C.
//   (exact: fl(a+b) is order-independent for two addends on a zeroed base)
// vpt: z==2 writes C transposed as [4][1024][2048] (vp^T direct).
// ---------------------------------------------------------------------------
template <int OUT_BF16, int SPLITK>
__global__ __launch_bounds__(256) void gemm_bt(
    const u16* __restrict__ A, const u16* __restrict__ B, void* __restrict__ Cv,
    int K, int lda, int ldb, int ldc,
    long long sA, long long sB, long long sC,
    float scale, int tri_grid, int causal_klimit,
    int vpt, u16* __restrict__ vpC) {
  int bm, bn;
  int kt0 = 0;
  bool part0_heavy = false;
  bool atomic_out = false;
  if (tri_grid) {
    int bx = blockIdx.x;
    bx = (bx & 7) * 17 + (bx >> 3);  // bijective XCD swizzle (136 = 8*17)
    int i = (int)((sqrtf(8.f * bx + 1.f) - 1.f) * 0.5f);
    while ((i + 1) * (i + 2) / 2 <= bx) ++i;
    while (i * (i + 1) / 2 > bx) --i;
    bm = i;
    bn = bx - i * (i + 1) / 2;
  } else if (SPLITK) {
    const int bx = blockIdx.x;  // 0..23
    if (bx < 8) {
      bm = 8 + bx; part0_heavy = true; atomic_out = true;
    } else if (bx < 16) {
      bm = 15 - (bx - 8); kt0 = 32; atomic_out = true;
    } else {
      bm = 23 - bx;
    }
    bn = blockIdx.y;
  } else {
    bm = blockIdx.x;
    bn = blockIdx.y;
  }
  const int m0 = bm * 128;
  const int n0 = bn * 128;
  A += (size_t)blockIdx.z * sA;
  B += (size_t)blockIdx.z * sB;

  __shared__ u16 As[2][4096];
  __shared__ u16 Bs[2][4096];

  const int tid = threadIdx.x;
  const int lane = tid & 63;
  const int wid = tid >> 6;
  const int wm = (wid & 1) * 64;
  const int wn = (wid >> 1) * 64;
  const int fr = lane & 15;   // m/n within 16x16 frag
  const int fq = lane >> 4;   // logical k-segment

  floatx4 acc[4][4] = {};

  int kt_end = K >> 5;
  if (causal_klimit) {
    int lim = (m0 >> 5) + 4;
    if (lim < kt_end) kt_end = lim;
  }
  if (part0_heavy && kt_end > 32) kt_end = 32;

  const int rowi = tid >> 2;                 // 0..63
  const int segi = tid & 3;                  // physical 16B seg
  const int sgz = segi ^ ((rowi >> 1) & 3);  // logical seg to fetch
  const u16* gA = A + (size_t)(m0 + rowi) * lda + sgz * 8;
  const u16* gB = B + (size_t)(n0 + rowi) * ldb + sgz * 8;

  // fragment read offsets (swizzled), within one 4096-elem buffer
  int offA[4], offB[4];
#pragma unroll
  for (int i = 0; i < 4; ++i) {
    int ra = wm + i * 16 + fr;
    offA[i] = ra * 32 + (fq ^ ((ra >> 1) & 3)) * 8;
    int rb = wn + i * 16 + fr;
    offB[i] = rb * 32 + (fq ^ ((rb >> 1) & 3)) * 8;
  }

  auto issue = [&](int kt) {
    const int k0 = kt << 5;
    const int odd = kt & 1;
    async16(gA + k0, &As[odd][tid * 8]);
    async16(gA + k0 + (size_t)64 * lda, &As[odd][tid * 8 + 2048]);
    async16(gB + k0, &Bs[odd][tid * 8]);
    async16(gB + k0 + (size_t)64 * ldb, &Bs[odd][tid * 8 + 2048]);
  };

  issue(kt0);
  for (int kt = kt0; kt < kt_end; ++kt) {
    if (kt + 1 < kt_end) {
      issue(kt + 1);
      __builtin_amdgcn_s_waitcnt(WAIT_VM4);  // tile kt's 4 loads retired
    } else {
      __builtin_amdgcn_s_waitcnt(WAIT_VM0);
    }
    asm volatile("s_barrier" ::: "memory");

    const u16* ab = As[kt & 1];
    const u16* bb = Bs[kt & 1];
    short8 av[4], bv[4];
#pragma unroll
    for (int i = 0; i < 4; ++i) av[i] = *(const short8*)(ab + offA[i]);
#pragma unroll
    for (int j = 0; j < 4; ++j) bv[j] = *(const short8*)(bb + offB[j]);

#pragma unroll
    for (int i = 0; i < 4; ++i)
#pragma unroll
      for (int j = 0; j < 4; ++j)
        acc[i][j] = __builtin_amdgcn_mfma_f32_16x16x32_bf16(av[i], bv[j],
                                                            acc[i][j], 0, 0, 0);
    asm volatile("s_barrier" ::: "memory");  // readers done before overwrite
  }

  // Epilogue. C/D layout: col = lane&15 (=fr), row = fq*4 + reg.
  if (vpt && blockIdx.z == 2) {
    // write transposed: vpC[b][n][t], b = m>>11, t = m&2047 (T=2048, H=1024)
#pragma unroll
    for (int i = 0; i < 4; ++i) {
      const int m = m0 + wm + i * 16 + fq * 4;
      const int b = m >> 11, t = m & 2047;
#pragma unroll
      for (int j = 0; j < 4; ++j) {
        const int n = n0 + wn + j * 16 + fr;
        u16x4 o;
#pragma unroll
        for (int r = 0; r < 4; ++r) o[r] = f2bf(acc[i][j][r]);
        *(u16x4*)&vpC[(size_t)b * 2097152 + (size_t)n * 2048 + t] = o;
      }
    }
    return;
  }
  if (OUT_BF16) {
    u16* C = (u16*)Cv + (size_t)blockIdx.z * sC;
#pragma unroll
    for (int i = 0; i < 4; ++i) {
      const int m = m0 + wm + i * 16 + fq * 4;
#pragma unroll
      for (int j = 0; j < 4; ++j) {
        const int n = n0 + wn + j * 16 + fr;
#pragma unroll
        for (int r = 0; r < 4; ++r)
          C[(size_t)(m + r) * ldc + n] = f2bf(acc[i][j][r] * scale);
      }
    }
  } else {
    float* C = (float*)Cv + (size_t)blockIdx.z * sC;
    if (SPLITK && atomic_out) {
#pragma unroll
      for (int i = 0; i < 4; ++i) {
        const int m = m0 + wm + i * 16 + fq * 4;
#pragma unroll
        for (int j = 0; j < 4; ++j) {
          const int n = n0 + wn + j * 16 + fr;
#pragma unroll
          for (int r = 0; r < 4; ++r)
            unsafeAtomicAdd(&C[(size_t)(m + r) * ldc + n],
                            acc[i][j][r] * scale);
        }
      }
    } else {
#pragma unroll
      for (int i = 0; i < 4; ++i) {
        const int m = m0 + wm + i * 16 + fq * 4;
#pragma unroll
        for (int j = 0; j < 4; ++j) {
          const int n = n0 + wn + j * 16 + fr;
#pragma unroll
          for (int r = 0; r < 4; ++r)
            C[(size_t)(m + r) * ldc + n] = acc[i][j][r] * scale;
        }
      }
    }
  }
}

// ---------------------------------------------------------------------------
// Fused prep: ONE dispatch for
//   blocks [0, 12288):      cast q,k,v fp32->bf16 (4096 blocks each)
//   blocks [12288, 13056):  W transpose+cast (Wq,Wk,Wq -> [H][C], 256 ea)
//   blocks [13056, 17152):  zero split-K atomic region out[z][1024:2048][:]
// All parts independent, memory-bound; fusing removes 2 dispatch gaps.
// ---------------------------------------------------------------------------
__global__ __launch_bounds__(256) void prep(
    const float* __restrict__ q, const float* __restrict__ k,
    const float* __restrict__ v, const float* __restrict__ Wq,
    const float* __restrict__ Wk, u16* __restrict__ qkv,
    u16* __restrict__ WT, float* __restrict__ out) {
  __shared__ u16 tile[64][72];
  const int bx = blockIdx.x;
  const int tid = threadIdx.x;

  if (bx < 12288) {  // ---- cast q/k/v: 4096 blocks per source ----
    const int z = bx >> 12;            // 0..2
    const int i = (bx & 4095) * 256 + tid;  // ushort8 index, n8 = 1048576
    const float* src = z == 0 ? q : (z == 1 ? k : v);
    u16* dst = qkv + (size_t)z * 8388608;
    floatx4 a = ((const floatx4*)src)[i * 2];
    floatx4 b = ((const floatx4*)src)[i * 2 + 1];
    ushort8 o;
#pragma unroll
    for (int j = 0; j < 4; ++j) { o[j] = f2bf(a[j]); o[4 + j] = f2bf(b[j]); }
    ((ushort8*)dst)[i] = o;
    return;
  }
  if (bx < 13056) {  // ---- W transpose: 256 blocks per W slot ----
    const int idx = bx - 12288;
    const int zw = idx >> 8;           // 0..2 (Wq, Wk, Wq)
    const int rem = idx & 255;
    const int r0 = (rem >> 4) * 64;    // C/64 = 16
    const int c0 = (rem & 15) * 64;    // H/64 = 16
    const int R = 1024, C = 1024;
    const float* in = (zw == 1) ? Wk : Wq;
    u16* dst = WT + (size_t)zw * R * C;
#pragma unroll
    for (int rnd = 0; rnd < 2; ++rnd) {
      int e = rnd * 256 + tid;
      int rr = e >> 3, seg = e & 7;
      const float* p = &in[(size_t)(r0 + rr) * C + c0 + seg * 8];
      floatx4 a = *(const floatx4*)p;
      floatx4 b = *(const floatx4*)(p + 4);
      u16* tp = &tile[rr][seg * 8];
#pragma unroll
      for (int j = 0; j < 4; ++j) { tp[j] = f2bf(a[j]); tp[4 + j] = f2bf(b[j]); }
    }
    __syncthreads();
#pragma unroll
    for (int rnd = 0; rnd < 2; ++rnd) {
      int e = rnd * 256 + tid;
      int cc = e >> 3, rseg = e & 7;
      ushort8 tv;
#pragma unroll
      for (int j = 0; j < 8; ++j) tv[j] = tile[rseg * 8 + j][cc];
      *(ushort8*)&dst[(size_t)(c0 + cc) * R + r0 + rseg * 8] = tv;
    }
    return;
  }
  {  // ---- zero split-K atomic region: 4096 blocks ----
    const size_t i = (size_t)(bx - 13056) * 256 + tid;  // float4 index
    const size_t z = i >> 18;          // 262144 float4 per batch-half
    const size_t r = i & 262143;
    floatx4* p = (floatx4*)(out + z * 2097152 + 1048576) + r;
    *p = floatx4{0.f, 0.f, 0.f, 0.f};
  }
}

// Causal row softmax, bf16 in-place, single pass (T=2048).
// All per-thread state statically indexed (rule #20); one 16B load + one 16B
// store per thread; masked lanes write exp(-huge)*inv = 0 (upper-tri fill).
__global__ __launch_bounds__(256) void softmax_causal(u16* __restrict__ S,
                                                      int T) {
  const int row = blockIdx.x;
  const int t = row & (T - 1);
  const int len = t + 1;
  u16* srow = S + (size_t)row * T;
  const int tid = threadIdx.x;
  const int base = tid * 8;

  const ushort8 raw = *(const ushort8*)(srow + base);
  float v[8];
  float mx = -1e30f;
#pragma unroll
  for (int j = 0; j < 8; ++j) {
    const float f = bf2f(raw[j]);
    v[j] = (base + j < len) ? f : -1e30f;
    mx = fmaxf(mx, v[j]);
  }
#pragma unroll
  for (int o = 32; o > 0; o >>= 1) mx = fmaxf(mx, __shfl_xor(mx, o, 64));

  __shared__ float red[8];
  if ((tid & 63) == 0) red[tid >> 6] = mx;
  __syncthreads();
  mx = fmaxf(fmaxf(red[0], red[1]), fmaxf(red[2], red[3]));

  float sum = 0.f;
#pragma unroll
  for (int j = 0; j < 8; ++j) {
    const float e = __expf(v[j] - mx);  // masked lanes: exp(-huge) = 0
    v[j] = e;
    sum += e;
  }
#pragma unroll
  for (int o = 32; o > 0; o >>= 1) sum += __shfl_xor(sum, o, 64);
  if ((tid & 63) == 0) red[4 + (tid >> 6)] = sum;
  __syncthreads();
  sum = red[4] + red[5] + red[6] + red[7];
  const float inv = 1.f / sum;

  ushort8 o8;
#pragma unroll
  for (int j = 0; j < 8; ++j) o8[j] = f2bf(v[j] * inv);
  *(ushort8*)(srow + base) = o8;
}

extern "C" void kernel_launch(void* const* d_in, const int* in_sizes, int n_in,
                              void* d_out, int out_size, void* d_ws,
                              size_t ws_size, hipStream_t stream) {
  (void)in_sizes; (void)n_in; (void)out_size; (void)ws_size;
  const float* k  = (const float*)d_in[1];
  const float* q  = (const float*)d_in[2];
  const float* v  = (const float*)d_in[3];
  const float* Wk = (const float*)d_in[4];
  const float* Wq = (const float*)d_in[5];
  float* out = (float*)d_out;

  const int B = 4, T = 2048, C = 1024, H = 1024;
  const int M = B * T;  // 8192
  const size_t MC = (size_t)M * C, CH = (size_t)C * H, MH = (size_t)M * H;

  u16* qkv  = (u16*)d_ws;        // 3 slots [M][C] bf16 (q,k,v)        50 MB
  u16* WT   = qkv + 3 * MC;      // 3 slots [H][C] bf16 (Wq,Wk,Wq)      6 MB
  u16* qkvp = WT + 3 * CH;       // slot0 qp, slot1 kp [M][H]          34 MB
  u16* vpT  = qkvp + 2 * MH;     // [B][H][T] bf16 (vp^T, direct)      17 MB
  u16* Sb   = vpT + MH;          // [B][T][T] bf16 (S, then P)       33.5 MB

  // 1) fused prep: cast q/k/v + W transposes + split-K zero (one dispatch)
  prep<<<dim3(17152), 256, 0, stream>>>(q, k, v, Wq, Wk, qkv, WT, out);

  // 2) qp = q*Wq, kp = k*Wk, vp^T = (v*Wq)^T (one batched dispatch, z=0..2)
  gemm_bt<1, 0><<<dim3(M / 128, H / 128, 3), 256, 0, stream>>>(
      qkv, WT, qkvp, C, C, C, H,
      (long long)MC, (long long)CH, (long long)MH, 1.f, 0, 0, 1, vpT);

  // 3) S = qp*kp^T / 32 (bf16), compact lower-triangle grid, XCD swizzle
  gemm_bt<1, 0><<<dim3(136, 1, B), 256, 0, stream>>>(
      qkvp, qkvp + MH, Sb, H, H, H, T,
      (long long)T * H, (long long)T * H, (long long)T * T,
      0.03125f, 1, 0, 0, nullptr);

  // 4) causal softmax in-place
  softmax_causal<<<dim3(B * T), 256, 0, stream>>>(Sb, T);

  // 5) out = P * vpT^T, causal klimit, split-K (24 slots: heavy halves first)
  gemm_bt<0, 1><<<dim3(24, H / 128, B), 256, 0, stream>>>(
      Sb, vpT, out, T, T, T, H,
      (long long)T * T, (long long)H * T, (long long)T * H,
      1.f, 0, 1, 0, nullptr);
}